// Round 1
// baseline (700.245 us; speedup 1.0000x reference)
//
#include <hip/hip_runtime.h>

#define BN_EPS 1e-5f

// ---------------- CSR build ----------------
__global__ __launch_bounds__(256) void hist_kernel(const int* __restrict__ ei, int E,
                                                   int* __restrict__ cnt) {
    int i = blockIdx.x * blockDim.x + threadIdx.x;
    int stride = gridDim.x * blockDim.x;
    for (int e = i; e < E; e += stride) {
        int d = ei[E + e];  // dst row of edge_index
        atomicAdd(&cnt[d], 1);
    }
}

// single block, 1024 threads: exclusive scan of cnt[0..N) -> row_ptr & pos
__global__ __launch_bounds__(1024) void scan_kernel(const int* __restrict__ cnt,
                                                    int* __restrict__ row_ptr,
                                                    int* __restrict__ pos, int N) {
    __shared__ int wsum[16];
    int tid = threadIdx.x;
    int lane = tid & 63;
    int wv = tid >> 6;
    int carry = 0;  // uniform across all threads
    for (int base = 0; base < N; base += 4096) {
        int i0 = base + tid * 4;
        int a0 = (i0 + 0 < N) ? cnt[i0 + 0] : 0;
        int a1 = (i0 + 1 < N) ? cnt[i0 + 1] : 0;
        int a2 = (i0 + 2 < N) ? cnt[i0 + 2] : 0;
        int a3 = (i0 + 3 < N) ? cnt[i0 + 3] : 0;
        int tot = a0 + a1 + a2 + a3;
        int s = tot;
#pragma unroll
        for (int off = 1; off < 64; off <<= 1) {
            int t = __shfl_up(s, off, 64);
            if (lane >= off) s += t;
        }
        if (lane == 63) wsum[wv] = s;
        __syncthreads();
        if (wv == 0) {
            int t = (lane < 16) ? wsum[lane] : 0;
#pragma unroll
            for (int off = 1; off < 16; off <<= 1) {
                int u = __shfl_up(t, off, 64);
                if (lane >= off) t += u;
            }
            if (lane < 16) wsum[lane] = t;  // inclusive wave-sums
        }
        __syncthreads();
        int waveoff = (wv == 0) ? 0 : wsum[wv - 1];
        int chunk_total = wsum[15];
        int excl = carry + waveoff + (s - tot);
        int o0 = excl, o1 = o0 + a0, o2 = o1 + a1, o3 = o2 + a2;
        if (i0 + 0 < N) { row_ptr[i0 + 0] = o0; pos[i0 + 0] = o0; }
        if (i0 + 1 < N) { row_ptr[i0 + 1] = o1; pos[i0 + 1] = o1; }
        if (i0 + 2 < N) { row_ptr[i0 + 2] = o2; pos[i0 + 2] = o2; }
        if (i0 + 3 < N) { row_ptr[i0 + 3] = o3; pos[i0 + 3] = o3; }
        carry += chunk_total;
        __syncthreads();  // protect wsum before next chunk's writes
    }
    if (tid == 0) row_ptr[N] = carry;
}

__global__ __launch_bounds__(256) void scatter_kernel(const int* __restrict__ ei, int E,
                                                      int* __restrict__ pos,
                                                      int* __restrict__ esrc) {
    int i = blockIdx.x * blockDim.x + threadIdx.x;
    int stride = gridDim.x * blockDim.x;
    for (int e = i; e < E; e += stride) {
        int s = ei[e];
        int d = ei[E + e];
        int idx = atomicAdd(&pos[d], 1);
        esrc[idx] = s;
    }
}

// ---------------- dense: Y[n][64] = X[n][K] @ W[64][K]^T (no bias) ----------------
template <int K>
__global__ __launch_bounds__(256) void linear_kernel(const float* __restrict__ X,
                                                     const float* __restrict__ W,
                                                     float* __restrict__ Y, int N) {
    __shared__ float wlds[K * 64];
    __shared__ float xlds[16 * K];
    int tid = threadIdx.x;
    // stage W in float4-k-major layout: (k,o) -> (k>>2)*256 + o*4 + (k&3)
    for (int j = tid; j < 64 * K; j += 256) {
        int o = j / K, k = j % K;
        wlds[(k >> 2) * 256 + o * 4 + (k & 3)] = W[j];
    }
    __syncthreads();
    const float4* w4p = (const float4*)wlds;
    const float4* x4p = (const float4*)xlds;
    int wv = tid >> 6, lane = tid & 63;
    for (int nb = blockIdx.x * 16; nb < N; nb += gridDim.x * 16) {
        const float4* xg = (const float4*)(X + (size_t)nb * K);
        float4* xl = (float4*)xlds;
        for (int j = tid; j < 16 * K / 4; j += 256) xl[j] = xg[j];
        __syncthreads();
        int r = wv * 4;
        float a0 = 0.f, a1 = 0.f, a2 = 0.f, a3 = 0.f;
#pragma unroll 8
        for (int kb = 0; kb < K / 4; kb++) {
            float4 w = w4p[kb * 64 + lane];
            float4 x0 = x4p[(r + 0) * (K / 4) + kb];
            float4 x1 = x4p[(r + 1) * (K / 4) + kb];
            float4 x2 = x4p[(r + 2) * (K / 4) + kb];
            float4 x3 = x4p[(r + 3) * (K / 4) + kb];
            a0 += x0.x * w.x + x0.y * w.y + x0.z * w.z + x0.w * w.w;
            a1 += x1.x * w.x + x1.y * w.y + x1.z * w.z + x1.w * w.w;
            a2 += x2.x * w.x + x2.y * w.y + x2.z * w.z + x2.w * w.w;
            a3 += x3.x * w.x + x3.y * w.y + x3.z * w.z + x3.w * w.w;
        }
        Y[(size_t)(nb + r + 0) * 64 + lane] = a0;
        Y[(size_t)(nb + r + 1) * 64 + lane] = a1;
        Y[(size_t)(nb + r + 2) * 64 + lane] = a2;
        Y[(size_t)(nb + r + 3) * 64 + lane] = a3;
        __syncthreads();
    }
}

// ---------------- gather: T[i] = relu(Y[i] + bias + sum_{e in CSR(i)} Y[src[e]]) ----------------
__global__ __launch_bounds__(256) void gather_kernel(const float* __restrict__ Y,
                                                     const int* __restrict__ row_ptr,
                                                     const int* __restrict__ esrc,
                                                     const float* __restrict__ bias,
                                                     float* __restrict__ T, int N) {
    int wv = threadIdx.x >> 6, lane = threadIdx.x & 63;
    int node = blockIdx.x * 4 + wv;
    if (node >= N) return;
    float acc = Y[(size_t)node * 64 + lane] + bias[lane];
    int e0 = row_ptr[node], e1 = row_ptr[node + 1];
    int e = e0;
    for (; e + 4 <= e1; e += 4) {
        int s0 = esrc[e], s1 = esrc[e + 1], s2 = esrc[e + 2], s3 = esrc[e + 3];
        float f0 = Y[(size_t)s0 * 64 + lane];
        float f1 = Y[(size_t)s1 * 64 + lane];
        float f2 = Y[(size_t)s2 * 64 + lane];
        float f3 = Y[(size_t)s3 * 64 + lane];
        acc += (f0 + f1) + (f2 + f3);
    }
    for (; e < e1; e++) acc += Y[(size_t)esrc[e] * 64 + lane];
    T[(size_t)node * 64 + lane] = fmaxf(acc, 0.f);
}

// ---------------- fused: Y = (relu(bn(T@W1^T + b1))) @ W2^T  (h1 never hits HBM) ------------
__global__ __launch_bounds__(256) void fused_mlp2_kernel(
    const float* __restrict__ T, const float* __restrict__ W1, const float* __restrict__ b1,
    const float* __restrict__ g, const float* __restrict__ be, const float* __restrict__ m,
    const float* __restrict__ v, const float* __restrict__ W2, float* __restrict__ Y, int N) {
    __shared__ float w1lds[64 * 64];
    __shared__ float w2lds[64 * 64];
    __shared__ float tl[16 * 64];
    __shared__ float hl[16 * 64];
    int tid = threadIdx.x, wv = tid >> 6, lane = tid & 63;
    for (int j = tid; j < 4096; j += 256) {
        int o = j >> 6, k = j & 63;
        int idx = (k >> 2) * 256 + o * 4 + (k & 3);
        w1lds[idx] = W1[j];
        w2lds[idx] = W2[j];
    }
    float bias = b1[lane];
    float s = g[lane] * rsqrtf(v[lane] + BN_EPS);
    float c = be[lane] - m[lane] * s;
    __syncthreads();
    const float4* w14 = (const float4*)w1lds;
    const float4* w24 = (const float4*)w2lds;
    const float4* t4 = (const float4*)tl;
    const float4* h4 = (const float4*)hl;
    for (int nb = blockIdx.x * 16; nb < N; nb += gridDim.x * 16) {
        const float4* tg = (const float4*)(T + (size_t)nb * 64);
        float4* tw = (float4*)tl;
        for (int j = tid; j < 256; j += 256) tw[j] = tg[j];
        __syncthreads();
        int r = wv * 4;
        float a0 = bias, a1 = bias, a2 = bias, a3 = bias;
#pragma unroll
        for (int kb = 0; kb < 16; kb++) {
            float4 w = w14[kb * 64 + lane];
            float4 x0 = t4[(r + 0) * 16 + kb];
            float4 x1 = t4[(r + 1) * 16 + kb];
            float4 x2 = t4[(r + 2) * 16 + kb];
            float4 x3 = t4[(r + 3) * 16 + kb];
            a0 += x0.x * w.x + x0.y * w.y + x0.z * w.z + x0.w * w.w;
            a1 += x1.x * w.x + x1.y * w.y + x1.z * w.z + x1.w * w.w;
            a2 += x2.x * w.x + x2.y * w.y + x2.z * w.z + x2.w * w.w;
            a3 += x3.x * w.x + x3.y * w.y + x3.z * w.z + x3.w * w.w;
        }
        a0 = fmaxf(a0 * s + c, 0.f);
        a1 = fmaxf(a1 * s + c, 0.f);
        a2 = fmaxf(a2 * s + c, 0.f);
        a3 = fmaxf(a3 * s + c, 0.f);
        hl[(r + 0) * 64 + lane] = a0;
        hl[(r + 1) * 64 + lane] = a1;
        hl[(r + 2) * 64 + lane] = a2;
        hl[(r + 3) * 64 + lane] = a3;
        __syncthreads();
        float o0 = 0.f, o1 = 0.f, o2 = 0.f, o3 = 0.f;
#pragma unroll
        for (int kb = 0; kb < 16; kb++) {
            float4 w = w24[kb * 64 + lane];
            float4 x0 = h4[(r + 0) * 16 + kb];
            float4 x1 = h4[(r + 1) * 16 + kb];
            float4 x2 = h4[(r + 2) * 16 + kb];
            float4 x3 = h4[(r + 3) * 16 + kb];
            o0 += x0.x * w.x + x0.y * w.y + x0.z * w.z + x0.w * w.w;
            o1 += x1.x * w.x + x1.y * w.y + x1.z * w.z + x1.w * w.w;
            o2 += x2.x * w.x + x2.y * w.y + x2.z * w.z + x2.w * w.w;
            o3 += x3.x * w.x + x3.y * w.y + x3.z * w.z + x3.w * w.w;
        }
        Y[(size_t)(nb + r + 0) * 64 + lane] = o0;
        Y[(size_t)(nb + r + 1) * 64 + lane] = o1;
        Y[(size_t)(nb + r + 2) * 64 + lane] = o2;
        Y[(size_t)(nb + r + 3) * 64 + lane] = o3;
        __syncthreads();
    }
}

// ---------------- H = relu(bn(T@W^T + b)) ----------------
__global__ __launch_bounds__(256) void fused_mlp1_kernel(
    const float* __restrict__ T, const float* __restrict__ W, const float* __restrict__ b,
    const float* __restrict__ g, const float* __restrict__ be, const float* __restrict__ m,
    const float* __restrict__ v, float* __restrict__ H, int N) {
    __shared__ float wlds[64 * 64];
    __shared__ float tl[16 * 64];
    int tid = threadIdx.x, wv = tid >> 6, lane = tid & 63;
    for (int j = tid; j < 4096; j += 256) {
        int o = j >> 6, k = j & 63;
        wlds[(k >> 2) * 256 + o * 4 + (k & 3)] = W[j];
    }
    float bias = b[lane];
    float s = g[lane] * rsqrtf(v[lane] + BN_EPS);
    float c = be[lane] - m[lane] * s;
    __syncthreads();
    const float4* w4 = (const float4*)wlds;
    const float4* t4 = (const float4*)tl;
    for (int nb = blockIdx.x * 16; nb < N; nb += gridDim.x * 16) {
        const float4* tg = (const float4*)(T + (size_t)nb * 64);
        float4* tw = (float4*)tl;
        for (int j = tid; j < 256; j += 256) tw[j] = tg[j];
        __syncthreads();
        int r = wv * 4;
        float a0 = bias, a1 = bias, a2 = bias, a3 = bias;
#pragma unroll
        for (int kb = 0; kb < 16; kb++) {
            float4 w = w4[kb * 64 + lane];
            float4 x0 = t4[(r + 0) * 16 + kb];
            float4 x1 = t4[(r + 1) * 16 + kb];
            float4 x2 = t4[(r + 2) * 16 + kb];
            float4 x3 = t4[(r + 3) * 16 + kb];
            a0 += x0.x * w.x + x0.y * w.y + x0.z * w.z + x0.w * w.w;
            a1 += x1.x * w.x + x1.y * w.y + x1.z * w.z + x1.w * w.w;
            a2 += x2.x * w.x + x2.y * w.y + x2.z * w.z + x2.w * w.w;
            a3 += x3.x * w.x + x3.y * w.y + x3.z * w.z + x3.w * w.w;
        }
        H[(size_t)(nb + r + 0) * 64 + lane] = fmaxf(a0 * s + c, 0.f);
        H[(size_t)(nb + r + 1) * 64 + lane] = fmaxf(a1 * s + c, 0.f);
        H[(size_t)(nb + r + 2) * 64 + lane] = fmaxf(a2 * s + c, 0.f);
        H[(size_t)(nb + r + 3) * 64 + lane] = fmaxf(a3 * s + c, 0.f);
        __syncthreads();
    }
}

// ---------------- mean pool per graph (batch is sorted) ----------------
__global__ __launch_bounds__(256) void pool_kernel(const float* __restrict__ H,
                                                   const int* __restrict__ batch,
                                                   float* __restrict__ out, int N) {
    __shared__ float part[4][64];
    int g = blockIdx.x;
    int tid = threadIdx.x, wv = tid >> 6, lane = tid & 63;
    int lo = 0, hi = N;
    while (lo < hi) { int mid = (lo + hi) >> 1; if (batch[mid] < g) lo = mid + 1; else hi = mid; }
    int start = lo;
    hi = N;
    while (lo < hi) { int mid = (lo + hi) >> 1; if (batch[mid] < g + 1) lo = mid + 1; else hi = mid; }
    int end = lo;
    float acc = 0.f;
    for (int i = start + wv; i < end; i += 4) acc += H[(size_t)i * 64 + lane];
    part[wv][lane] = acc;
    __syncthreads();
    if (tid < 64) {
        float sfin = part[0][tid] + part[1][tid] + part[2][tid] + part[3][tid];
        float cnt = (float)(end - start);
        out[(size_t)g * 64 + tid] = sfin / fmaxf(cnt, 1.f);
    }
}

extern "C" void kernel_launch(void* const* d_in, const int* in_sizes, int n_in,
                              void* d_out, int out_size, void* d_ws, size_t ws_size,
                              hipStream_t stream) {
    const float* x   = (const float*)d_in[0];
    const int*   ei  = (const int*)d_in[1];   // [2][E], row0=src row1=dst
    const int*   bat = (const int*)d_in[2];
    const float* W1a = (const float*)d_in[3];
    const float* b1a = (const float*)d_in[4];
    const float* W1b = (const float*)d_in[5];
    const float* b1b = (const float*)d_in[6];
    const float* g1  = (const float*)d_in[7];
    const float* be1 = (const float*)d_in[8];
    const float* m1  = (const float*)d_in[9];
    const float* v1  = (const float*)d_in[10];
    const float* W2a = (const float*)d_in[11];
    const float* b2a = (const float*)d_in[12];
    const float* W2b = (const float*)d_in[13];
    const float* b2b = (const float*)d_in[14];
    const float* g2  = (const float*)d_in[15];
    const float* be2 = (const float*)d_in[16];
    const float* m2  = (const float*)d_in[17];
    const float* v2  = (const float*)d_in[18];
    float* out = (float*)d_out;

    int N = in_sizes[0] / 128;
    int E = in_sizes[1] / 2;
    int G = out_size / 64;

    // workspace: row_ptr(N+1, padded) | pos(N) | esrc(E) | bufA(N*64) | bufB(N*64)  ~= 58.4 MB
    char* ws = (char*)d_ws;
    int* row_ptr = (int*)ws;
    int* pos = row_ptr + ((N + 1 + 3) & ~3);
    int* esrc = pos + N;
    float* bufA = (float*)(esrc + E);
    float* bufB = bufA + (size_t)N * 64;

    hipMemsetAsync(pos, 0, (size_t)N * sizeof(int), stream);
    hist_kernel<<<2048, 256, 0, stream>>>(ei, E, pos);
    scan_kernel<<<1, 1024, 0, stream>>>(pos, row_ptr, pos, N);
    scatter_kernel<<<2048, 256, 0, stream>>>(ei, E, pos, esrc);

    // layer 1: y1 = x@W1a^T ; t1 = relu(y1 + agg(y1) + b1a) ; y2 = relu(bn1(t1@W1b^T+b1b))@W2a^T
    linear_kernel<128><<<2048, 256, 0, stream>>>(x, W1a, bufA, N);
    gather_kernel<<<(N + 3) / 4, 256, 0, stream>>>(bufA, row_ptr, esrc, b1a, bufB, N);
    fused_mlp2_kernel<<<2048, 256, 0, stream>>>(bufB, W1b, b1b, g1, be1, m1, v1, W2a, bufA, N);

    // layer 2: t2 = relu(y2 + agg(y2) + b2a) ; h2 = relu(bn2(t2@W2b^T+b2b))
    gather_kernel<<<(N + 3) / 4, 256, 0, stream>>>(bufA, row_ptr, esrc, b2a, bufB, N);
    fused_mlp1_kernel<<<2048, 256, 0, stream>>>(bufB, W2b, b2b, g2, be2, m2, v2, bufA, N);

    // mean pool
    pool_kernel<<<G, 256, 0, stream>>>(bufA, bat, out, N);
}

// Round 2
// 638.025 us; speedup vs baseline: 1.0975x; 1.0975x over previous
//
#include <hip/hip_runtime.h>

#define BN_EPS 1e-5f

// ---------------- CSR build ----------------
__global__ __launch_bounds__(256) void hist_kernel(const int* __restrict__ ei, int E,
                                                   int* __restrict__ cnt) {
    int i = blockIdx.x * blockDim.x + threadIdx.x;
    int stride = gridDim.x * blockDim.x;
    for (int e = i; e < E; e += stride) {
        int d = ei[E + e];  // dst row of edge_index
        atomicAdd(&cnt[d], 1);
    }
}

// phase 1: per-block sums of 1024-element chunks
__global__ __launch_bounds__(256) void scan_p1(const int* __restrict__ cnt,
                                               int* __restrict__ bsum, int N) {
    __shared__ int ws[4];
    int b = blockIdx.x, tid = threadIdx.x;
    int i0 = b * 1024 + tid * 4;
    int a0 = (i0 + 0 < N) ? cnt[i0 + 0] : 0;
    int a1 = (i0 + 1 < N) ? cnt[i0 + 1] : 0;
    int a2 = (i0 + 2 < N) ? cnt[i0 + 2] : 0;
    int a3 = (i0 + 3 < N) ? cnt[i0 + 3] : 0;
    int tot = a0 + a1 + a2 + a3;
#pragma unroll
    for (int off = 32; off >= 1; off >>= 1) tot += __shfl_down(tot, off, 64);
    if ((tid & 63) == 0) ws[tid >> 6] = tot;
    __syncthreads();
    if (tid == 0) bsum[b] = ws[0] + ws[1] + ws[2] + ws[3];
}

// phase 2: single block scans up to 1024 block-sums -> exclusive offsets + grand total
__global__ __launch_bounds__(1024) void scan_p2(const int* __restrict__ bsum,
                                                int* __restrict__ boff, int nb,
                                                int* __restrict__ total_out) {
    __shared__ int wsum[16];
    int tid = threadIdx.x, lane = tid & 63, wv = tid >> 6;
    int val = (tid < nb) ? bsum[tid] : 0;
    int s = val;
#pragma unroll
    for (int off = 1; off < 64; off <<= 1) {
        int t = __shfl_up(s, off, 64);
        if (lane >= off) s += t;
    }
    if (lane == 63) wsum[wv] = s;
    __syncthreads();
    if (wv == 0) {
        int t = (lane < 16) ? wsum[lane] : 0;
#pragma unroll
        for (int off = 1; off < 16; off <<= 1) {
            int u = __shfl_up(t, off, 64);
            if (lane >= off) t += u;
        }
        if (lane < 16) wsum[lane] = t;
    }
    __syncthreads();
    int excl = ((wv == 0) ? 0 : wsum[wv - 1]) + s - val;
    if (tid < nb) boff[tid] = excl;
    if (tid == 0) *total_out = wsum[15];
}

// phase 3: local scan + block offset -> row_ptr & pos (reads cnt, overwrites pos in place)
__global__ __launch_bounds__(256) void scan_p3(const int* __restrict__ cnt,
                                               const int* __restrict__ boff,
                                               int* __restrict__ row_ptr,
                                               int* __restrict__ pos, int N) {
    __shared__ int wsum[4];
    int b = blockIdx.x, tid = threadIdx.x, lane = tid & 63, wv = tid >> 6;
    int i0 = b * 1024 + tid * 4;
    int a0 = (i0 + 0 < N) ? cnt[i0 + 0] : 0;
    int a1 = (i0 + 1 < N) ? cnt[i0 + 1] : 0;
    int a2 = (i0 + 2 < N) ? cnt[i0 + 2] : 0;
    int a3 = (i0 + 3 < N) ? cnt[i0 + 3] : 0;
    int tot = a0 + a1 + a2 + a3;
    int s = tot;
#pragma unroll
    for (int off = 1; off < 64; off <<= 1) {
        int t = __shfl_up(s, off, 64);
        if (lane >= off) s += t;
    }
    if (lane == 63) wsum[wv] = s;
    __syncthreads();
    int waveoff = 0;
#pragma unroll
    for (int i = 0; i < 4; i++) waveoff += (i < wv) ? wsum[i] : 0;
    int excl = boff[b] + waveoff + (s - tot);
    int o0 = excl, o1 = o0 + a0, o2 = o1 + a1, o3 = o2 + a2;
    if (i0 + 0 < N) { row_ptr[i0 + 0] = o0; pos[i0 + 0] = o0; }
    if (i0 + 1 < N) { row_ptr[i0 + 1] = o1; pos[i0 + 1] = o1; }
    if (i0 + 2 < N) { row_ptr[i0 + 2] = o2; pos[i0 + 2] = o2; }
    if (i0 + 3 < N) { row_ptr[i0 + 3] = o3; pos[i0 + 3] = o3; }
}

__global__ __launch_bounds__(256) void scatter_kernel(const int* __restrict__ ei, int E,
                                                      int* __restrict__ pos,
                                                      int* __restrict__ esrc) {
    int i = blockIdx.x * blockDim.x + threadIdx.x;
    int stride = gridDim.x * blockDim.x;
    for (int e = i; e < E; e += stride) {
        int s = ei[e];
        int d = ei[E + e];
        int idx = atomicAdd(&pos[d], 1);
        // nt store: bypass cache write-allocate — random 4B scatter otherwise
        // amplifies to ~64B/line HBM write-back (measured 107MB for a 6.4MB array)
        __builtin_nontemporal_store(s, &esrc[idx]);
    }
}

// ---------------- dense: Y[n][64] = X[n][K] @ W[64][K]^T (no bias) ----------------
template <int K>
__global__ __launch_bounds__(256) void linear_kernel(const float* __restrict__ X,
                                                     const float* __restrict__ W,
                                                     float* __restrict__ Y, int N) {
    __shared__ float wlds[K * 64];
    __shared__ float xlds[16 * K];
    int tid = threadIdx.x;
    for (int j = tid; j < 64 * K; j += 256) {
        int o = j / K, k = j % K;
        wlds[(k >> 2) * 256 + o * 4 + (k & 3)] = W[j];
    }
    __syncthreads();
    const float4* w4p = (const float4*)wlds;
    const float4* x4p = (const float4*)xlds;
    int wv = tid >> 6, lane = tid & 63;
    for (int nb = blockIdx.x * 16; nb < N; nb += gridDim.x * 16) {
        const float4* xg = (const float4*)(X + (size_t)nb * K);
        float4* xl = (float4*)xlds;
        for (int j = tid; j < 16 * K / 4; j += 256) xl[j] = xg[j];
        __syncthreads();
        int r = wv * 4;
        float a0 = 0.f, a1 = 0.f, a2 = 0.f, a3 = 0.f;
#pragma unroll 8
        for (int kb = 0; kb < K / 4; kb++) {
            float4 w = w4p[kb * 64 + lane];
            float4 x0 = x4p[(r + 0) * (K / 4) + kb];
            float4 x1 = x4p[(r + 1) * (K / 4) + kb];
            float4 x2 = x4p[(r + 2) * (K / 4) + kb];
            float4 x3 = x4p[(r + 3) * (K / 4) + kb];
            a0 += x0.x * w.x + x0.y * w.y + x0.z * w.z + x0.w * w.w;
            a1 += x1.x * w.x + x1.y * w.y + x1.z * w.z + x1.w * w.w;
            a2 += x2.x * w.x + x2.y * w.y + x2.z * w.z + x2.w * w.w;
            a3 += x3.x * w.x + x3.y * w.y + x3.z * w.z + x3.w * w.w;
        }
        Y[(size_t)(nb + r + 0) * 64 + lane] = a0;
        Y[(size_t)(nb + r + 1) * 64 + lane] = a1;
        Y[(size_t)(nb + r + 2) * 64 + lane] = a2;
        Y[(size_t)(nb + r + 3) * 64 + lane] = a3;
        __syncthreads();
    }
}

// ---------------- gather: T[i] = relu(Y[i] + bias + sum_{e in CSR(i)} Y[src[e]]) ----------------
__global__ __launch_bounds__(256) void gather_kernel(const float* __restrict__ Y,
                                                     const int* __restrict__ row_ptr,
                                                     const int* __restrict__ esrc,
                                                     const float* __restrict__ bias,
                                                     float* __restrict__ T, int N) {
    int wv = threadIdx.x >> 6, lane = threadIdx.x & 63;
    int node = blockIdx.x * 4 + wv;
    if (node >= N) return;
    float acc = Y[(size_t)node * 64 + lane] + bias[lane];
    int e0 = row_ptr[node], e1 = row_ptr[node + 1];
    int e = e0;
    for (; e + 8 <= e1; e += 8) {
        int s0 = esrc[e], s1 = esrc[e + 1], s2 = esrc[e + 2], s3 = esrc[e + 3];
        int s4 = esrc[e + 4], s5 = esrc[e + 5], s6 = esrc[e + 6], s7 = esrc[e + 7];
        float f0 = Y[(size_t)s0 * 64 + lane];
        float f1 = Y[(size_t)s1 * 64 + lane];
        float f2 = Y[(size_t)s2 * 64 + lane];
        float f3 = Y[(size_t)s3 * 64 + lane];
        float f4 = Y[(size_t)s4 * 64 + lane];
        float f5 = Y[(size_t)s5 * 64 + lane];
        float f6 = Y[(size_t)s6 * 64 + lane];
        float f7 = Y[(size_t)s7 * 64 + lane];
        acc += ((f0 + f1) + (f2 + f3)) + ((f4 + f5) + (f6 + f7));
    }
    for (; e < e1; e++) acc += Y[(size_t)esrc[e] * 64 + lane];
    T[(size_t)node * 64 + lane] = fmaxf(acc, 0.f);
}

// ---------------- fused: Y = (relu(bn(T@W1^T + b1))) @ W2^T ----------------
__global__ __launch_bounds__(256) void fused_mlp2_kernel(
    const float* __restrict__ T, const float* __restrict__ W1, const float* __restrict__ b1,
    const float* __restrict__ g, const float* __restrict__ be, const float* __restrict__ m,
    const float* __restrict__ v, const float* __restrict__ W2, float* __restrict__ Y, int N) {
    __shared__ float w1lds[64 * 64];
    __shared__ float w2lds[64 * 64];
    __shared__ float tl[16 * 64];
    __shared__ float hl[16 * 64];
    int tid = threadIdx.x, wv = tid >> 6, lane = tid & 63;
    for (int j = tid; j < 4096; j += 256) {
        int o = j >> 6, k = j & 63;
        int idx = (k >> 2) * 256 + o * 4 + (k & 3);
        w1lds[idx] = W1[j];
        w2lds[idx] = W2[j];
    }
    float bias = b1[lane];
    float s = g[lane] * rsqrtf(v[lane] + BN_EPS);
    float c = be[lane] - m[lane] * s;
    __syncthreads();
    const float4* w14 = (const float4*)w1lds;
    const float4* w24 = (const float4*)w2lds;
    const float4* t4 = (const float4*)tl;
    const float4* h4 = (const float4*)hl;
    for (int nb = blockIdx.x * 16; nb < N; nb += gridDim.x * 16) {
        const float4* tg = (const float4*)(T + (size_t)nb * 64);
        float4* tw = (float4*)tl;
        for (int j = tid; j < 256; j += 256) tw[j] = tg[j];
        __syncthreads();
        int r = wv * 4;
        float a0 = bias, a1 = bias, a2 = bias, a3 = bias;
#pragma unroll
        for (int kb = 0; kb < 16; kb++) {
            float4 w = w14[kb * 64 + lane];
            float4 x0 = t4[(r + 0) * 16 + kb];
            float4 x1 = t4[(r + 1) * 16 + kb];
            float4 x2 = t4[(r + 2) * 16 + kb];
            float4 x3 = t4[(r + 3) * 16 + kb];
            a0 += x0.x * w.x + x0.y * w.y + x0.z * w.z + x0.w * w.w;
            a1 += x1.x * w.x + x1.y * w.y + x1.z * w.z + x1.w * w.w;
            a2 += x2.x * w.x + x2.y * w.y + x2.z * w.z + x2.w * w.w;
            a3 += x3.x * w.x + x3.y * w.y + x3.z * w.z + x3.w * w.w;
        }
        a0 = fmaxf(a0 * s + c, 0.f);
        a1 = fmaxf(a1 * s + c, 0.f);
        a2 = fmaxf(a2 * s + c, 0.f);
        a3 = fmaxf(a3 * s + c, 0.f);
        hl[(r + 0) * 64 + lane] = a0;
        hl[(r + 1) * 64 + lane] = a1;
        hl[(r + 2) * 64 + lane] = a2;
        hl[(r + 3) * 64 + lane] = a3;
        __syncthreads();
        float o0 = 0.f, o1 = 0.f, o2 = 0.f, o3 = 0.f;
#pragma unroll
        for (int kb = 0; kb < 16; kb++) {
            float4 w = w24[kb * 64 + lane];
            float4 x0 = h4[(r + 0) * 16 + kb];
            float4 x1 = h4[(r + 1) * 16 + kb];
            float4 x2 = h4[(r + 2) * 16 + kb];
            float4 x3 = h4[(r + 3) * 16 + kb];
            o0 += x0.x * w.x + x0.y * w.y + x0.z * w.z + x0.w * w.w;
            o1 += x1.x * w.x + x1.y * w.y + x1.z * w.z + x1.w * w.w;
            o2 += x2.x * w.x + x2.y * w.y + x2.z * w.z + x2.w * w.w;
            o3 += x3.x * w.x + x3.y * w.y + x3.z * w.z + x3.w * w.w;
        }
        Y[(size_t)(nb + r + 0) * 64 + lane] = o0;
        Y[(size_t)(nb + r + 1) * 64 + lane] = o1;
        Y[(size_t)(nb + r + 2) * 64 + lane] = o2;
        Y[(size_t)(nb + r + 3) * 64 + lane] = o3;
        __syncthreads();
    }
}

// ---------------- H = relu(bn(T@W^T + b)) ----------------
__global__ __launch_bounds__(256) void fused_mlp1_kernel(
    const float* __restrict__ T, const float* __restrict__ W, const float* __restrict__ b,
    const float* __restrict__ g, const float* __restrict__ be, const float* __restrict__ m,
    const float* __restrict__ v, float* __restrict__ H, int N) {
    __shared__ float wlds[64 * 64];
    __shared__ float tl[16 * 64];
    int tid = threadIdx.x, wv = tid >> 6, lane = tid & 63;
    for (int j = tid; j < 4096; j += 256) {
        int o = j >> 6, k = j & 63;
        wlds[(k >> 2) * 256 + o * 4 + (k & 3)] = W[j];
    }
    float bias = b[lane];
    float s = g[lane] * rsqrtf(v[lane] + BN_EPS);
    float c = be[lane] - m[lane] * s;
    __syncthreads();
    const float4* w4 = (const float4*)wlds;
    const float4* t4 = (const float4*)tl;
    for (int nb = blockIdx.x * 16; nb < N; nb += gridDim.x * 16) {
        const float4* tg = (const float4*)(T + (size_t)nb * 64);
        float4* tw = (float4*)tl;
        for (int j = tid; j < 256; j += 256) tw[j] = tg[j];
        __syncthreads();
        int r = wv * 4;
        float a0 = bias, a1 = bias, a2 = bias, a3 = bias;
#pragma unroll
        for (int kb = 0; kb < 16; kb++) {
            float4 w = w4[kb * 64 + lane];
            float4 x0 = t4[(r + 0) * 16 + kb];
            float4 x1 = t4[(r + 1) * 16 + kb];
            float4 x2 = t4[(r + 2) * 16 + kb];
            float4 x3 = t4[(r + 3) * 16 + kb];
            a0 += x0.x * w.x + x0.y * w.y + x0.z * w.z + x0.w * w.w;
            a1 += x1.x * w.x + x1.y * w.y + x1.z * w.z + x1.w * w.w;
            a2 += x2.x * w.x + x2.y * w.y + x2.z * w.z + x2.w * w.w;
            a3 += x3.x * w.x + x3.y * w.y + x3.z * w.z + x3.w * w.w;
        }
        H[(size_t)(nb + r + 0) * 64 + lane] = fmaxf(a0 * s + c, 0.f);
        H[(size_t)(nb + r + 1) * 64 + lane] = fmaxf(a1 * s + c, 0.f);
        H[(size_t)(nb + r + 2) * 64 + lane] = fmaxf(a2 * s + c, 0.f);
        H[(size_t)(nb + r + 3) * 64 + lane] = fmaxf(a3 * s + c, 0.f);
        __syncthreads();
    }
}

// ---------------- mean pool per graph (batch is sorted) ----------------
__global__ __launch_bounds__(256) void pool_kernel(const float* __restrict__ H,
                                                   const int* __restrict__ batch,
                                                   float* __restrict__ out, int N) {
    __shared__ float part[4][64];
    int g = blockIdx.x;
    int tid = threadIdx.x, wv = tid >> 6, lane = tid & 63;
    int lo = 0, hi = N;
    while (lo < hi) { int mid = (lo + hi) >> 1; if (batch[mid] < g) lo = mid + 1; else hi = mid; }
    int start = lo;
    hi = N;
    while (lo < hi) { int mid = (lo + hi) >> 1; if (batch[mid] < g + 1) lo = mid + 1; else hi = mid; }
    int end = lo;
    float acc = 0.f;
    for (int i = start + wv; i < end; i += 4) acc += H[(size_t)i * 64 + lane];
    part[wv][lane] = acc;
    __syncthreads();
    if (tid < 64) {
        float sfin = part[0][tid] + part[1][tid] + part[2][tid] + part[3][tid];
        float cnt = (float)(end - start);
        out[(size_t)g * 64 + tid] = sfin / fmaxf(cnt, 1.f);
    }
}

extern "C" void kernel_launch(void* const* d_in, const int* in_sizes, int n_in,
                              void* d_out, int out_size, void* d_ws, size_t ws_size,
                              hipStream_t stream) {
    const float* x   = (const float*)d_in[0];
    const int*   ei  = (const int*)d_in[1];   // [2][E], row0=src row1=dst
    const int*   bat = (const int*)d_in[2];
    const float* W1a = (const float*)d_in[3];
    const float* b1a = (const float*)d_in[4];
    const float* W1b = (const float*)d_in[5];
    const float* b1b = (const float*)d_in[6];
    const float* g1  = (const float*)d_in[7];
    const float* be1 = (const float*)d_in[8];
    const float* m1  = (const float*)d_in[9];
    const float* v1  = (const float*)d_in[10];
    const float* W2a = (const float*)d_in[11];
    const float* b2a = (const float*)d_in[12];
    const float* W2b = (const float*)d_in[13];
    const float* b2b = (const float*)d_in[14];
    const float* g2  = (const float*)d_in[15];
    const float* be2 = (const float*)d_in[16];
    const float* m2  = (const float*)d_in[17];
    const float* v2  = (const float*)d_in[18];
    float* out = (float*)d_out;

    int N = in_sizes[0] / 128;
    int E = in_sizes[1] / 2;
    int G = out_size / 64;

    // workspace layout
    char* ws = (char*)d_ws;
    int* row_ptr = (int*)ws;                       // N+1 (padded to 4)
    int* pos = row_ptr + ((N + 1 + 3) & ~3);       // N
    int* bsum = pos + N;                           // 1024
    int* boff = bsum + 1024;                       // 1024
    int* esrc = boff + 1024;                       // E
    float* bufA = (float*)(esrc + E);              // N*64
    float* bufB = bufA + (size_t)N * 64;           // N*64

    int nb = (N + 1023) / 1024;

    hipMemsetAsync(pos, 0, (size_t)N * sizeof(int), stream);
    hist_kernel<<<2048, 256, 0, stream>>>(ei, E, pos);
    scan_p1<<<nb, 256, 0, stream>>>(pos, bsum, N);
    scan_p2<<<1, 1024, 0, stream>>>(bsum, boff, nb, row_ptr + N);
    scan_p3<<<nb, 256, 0, stream>>>(pos, boff, row_ptr, pos, N);
    scatter_kernel<<<2048, 256, 0, stream>>>(ei, E, pos, esrc);

    // layer 1
    linear_kernel<128><<<2048, 256, 0, stream>>>(x, W1a, bufA, N);
    gather_kernel<<<(N + 3) / 4, 256, 0, stream>>>(bufA, row_ptr, esrc, b1a, bufB, N);
    fused_mlp2_kernel<<<2048, 256, 0, stream>>>(bufB, W1b, b1b, g1, be1, m1, v1, W2a, bufA, N);

    // layer 2
    gather_kernel<<<(N + 3) / 4, 256, 0, stream>>>(bufA, row_ptr, esrc, b2a, bufB, N);
    fused_mlp1_kernel<<<2048, 256, 0, stream>>>(bufB, W2b, b2b, g2, be2, m2, v2, bufA, N);

    // mean pool
    pool_kernel<<<G, 256, 0, stream>>>(bufA, bat, out, N);
}

// Round 3
// 482.972 us; speedup vs baseline: 1.4499x; 1.3210x over previous
//
#include <hip/hip_runtime.h>

#define BN_EPS 1e-5f
#define CHUNK 8192
#define MAXB 512  // max buckets (N up to 131072 with 256 nodes/bucket)

// ---------------- CSR build: bucketed, no global random scatter ----------------

// per-workgroup LDS histogram of dst>>8
__global__ __launch_bounds__(256) void bin_count(const int* __restrict__ ei, int E,
                                                 int* __restrict__ bcnt, int nbuck) {
    __shared__ int h[MAXB];
    for (int i = threadIdx.x; i < nbuck; i += 256) h[i] = 0;
    __syncthreads();
    int i = blockIdx.x * 256 + threadIdx.x, stride = gridDim.x * 256;
    for (int e = i; e < E; e += stride) {
        int d = ei[E + e];
        atomicAdd(&h[d >> 8], 1);
    }
    __syncthreads();
    for (int b = threadIdx.x; b < nbuck; b += 256)
        if (h[b]) atomicAdd(&bcnt[b], h[b]);
}

// single block: exclusive scan of bcnt[0..nbuck) -> boff, bpos; boff[nbuck]=E; row_ptr[N]=E
__global__ __launch_bounds__(512) void scan_small(const int* __restrict__ bcnt,
                                                  int* __restrict__ boff,
                                                  int* __restrict__ bpos,
                                                  int* __restrict__ row_ptr_end,
                                                  int nbuck, int E) {
    __shared__ int wsum[8];
    int tid = threadIdx.x, lane = tid & 63, wv = tid >> 6;
    int val = (tid < nbuck) ? bcnt[tid] : 0;
    int s = val;
#pragma unroll
    for (int off = 1; off < 64; off <<= 1) {
        int t = __shfl_up(s, off, 64);
        if (lane >= off) s += t;
    }
    if (lane == 63) wsum[wv] = s;
    __syncthreads();
    if (wv == 0) {
        int t = (lane < 8) ? wsum[lane] : 0;
#pragma unroll
        for (int off = 1; off < 8; off <<= 1) {
            int u = __shfl_up(t, off, 64);
            if (lane >= off) t += u;
        }
        if (lane < 8) wsum[lane] = t;
    }
    __syncthreads();
    int excl = ((wv == 0) ? 0 : wsum[wv - 1]) + s - val;
    if (tid < nbuck) { boff[tid] = excl; bpos[tid] = excl; }
    if (tid == 0) { boff[nbuck] = E; *row_ptr_end = E; }
}

// per 8192-edge chunk: LDS hist -> per-bucket global reserve -> ranked packed write.
// all writes to a given line come from one workgroup (one XCD) -> L2 coalesces.
__global__ __launch_bounds__(256) void bin_scatter(const int* __restrict__ ei, int E,
                                                   int* __restrict__ bpos,
                                                   int* __restrict__ binned, int nbuck) {
    __shared__ int h[MAXB];
    __shared__ int res[MAXB];
    int base = blockIdx.x * CHUNK;
    int cnt = min(CHUNK, E - base);
    for (int b = threadIdx.x; b < nbuck; b += 256) h[b] = 0;
    __syncthreads();
    for (int k = threadIdx.x; k < cnt; k += 256) {
        int d = ei[E + base + k];
        atomicAdd(&h[d >> 8], 1);
    }
    __syncthreads();
    for (int b = threadIdx.x; b < nbuck; b += 256) {
        int c = h[b];
        res[b] = c ? atomicAdd(&bpos[b], c) : 0;
        h[b] = 0;  // reuse as rank counter
    }
    __syncthreads();
    for (int k = threadIdx.x; k < cnt; k += 256) {
        int srcv = ei[base + k];
        int d = ei[E + base + k];
        int b = d >> 8;
        int r = atomicAdd(&h[b], 1);
        binned[res[b] + r] = ((d & 255) << 17) | srcv;  // src < 2^17
    }
}

// one workgroup per bucket: node counts -> LDS scan -> row_ptr, then ranked esrc
// scatter confined to a ~16KB window (single XCD L2 -> coalesced write-back).
__global__ __launch_bounds__(256) void bucket_csr(const int* __restrict__ binned,
                                                  const int* __restrict__ boff,
                                                  int* __restrict__ row_ptr,
                                                  int* __restrict__ esrc, int N) {
    __shared__ int ncnt[256];
    __shared__ int npos[256];
    __shared__ int wsum[4];
    int b = blockIdx.x, tid = threadIdx.x, lane = tid & 63, wv = tid >> 6;
    int lo = boff[b], hi = boff[b + 1];
    int base_node = b << 8;
    ncnt[tid] = 0;
    __syncthreads();
    for (int i = lo + tid; i < hi; i += 256)
        atomicAdd(&ncnt[binned[i] >> 17], 1);
    __syncthreads();
    int c = ncnt[tid];
    int s = c;
#pragma unroll
    for (int off = 1; off < 64; off <<= 1) {
        int t = __shfl_up(s, off, 64);
        if (lane >= off) s += t;
    }
    if (lane == 63) wsum[wv] = s;
    __syncthreads();
    int woff = 0;
#pragma unroll
    for (int i = 0; i < 4; i++) woff += (i < wv) ? wsum[i] : 0;
    int abspos = lo + woff + (s - c);
    if (base_node + tid < N) row_ptr[base_node + tid] = abspos;
    npos[tid] = abspos;
    __syncthreads();
    for (int i = lo + tid; i < hi; i += 256) {
        int val = binned[i];
        int r = atomicAdd(&npos[val >> 17], 1);
        esrc[r] = val & 0x1FFFF;
    }
}

// ---------------- dense: Y[n][64] = X[n][K] @ W[64][K]^T (no bias) ----------------
template <int K>
__global__ __launch_bounds__(256) void linear_kernel(const float* __restrict__ X,
                                                     const float* __restrict__ W,
                                                     float* __restrict__ Y, int N) {
    __shared__ float wlds[K * 64];
    __shared__ float xlds[16 * K];
    int tid = threadIdx.x;
    for (int j = tid; j < 64 * K; j += 256) {
        int o = j / K, k = j % K;
        wlds[(k >> 2) * 256 + o * 4 + (k & 3)] = W[j];
    }
    __syncthreads();
    const float4* w4p = (const float4*)wlds;
    const float4* x4p = (const float4*)xlds;
    int wv = tid >> 6, lane = tid & 63;
    for (int nb = blockIdx.x * 16; nb < N; nb += gridDim.x * 16) {
        const float4* xg = (const float4*)(X + (size_t)nb * K);
        float4* xl = (float4*)xlds;
        for (int j = tid; j < 16 * K / 4; j += 256) xl[j] = xg[j];
        __syncthreads();
        int r = wv * 4;
        float a0 = 0.f, a1 = 0.f, a2 = 0.f, a3 = 0.f;
#pragma unroll 8
        for (int kb = 0; kb < K / 4; kb++) {
            float4 w = w4p[kb * 64 + lane];
            float4 x0 = x4p[(r + 0) * (K / 4) + kb];
            float4 x1 = x4p[(r + 1) * (K / 4) + kb];
            float4 x2 = x4p[(r + 2) * (K / 4) + kb];
            float4 x3 = x4p[(r + 3) * (K / 4) + kb];
            a0 += x0.x * w.x + x0.y * w.y + x0.z * w.z + x0.w * w.w;
            a1 += x1.x * w.x + x1.y * w.y + x1.z * w.z + x1.w * w.w;
            a2 += x2.x * w.x + x2.y * w.y + x2.z * w.z + x2.w * w.w;
            a3 += x3.x * w.x + x3.y * w.y + x3.z * w.z + x3.w * w.w;
        }
        Y[(size_t)(nb + r + 0) * 64 + lane] = a0;
        Y[(size_t)(nb + r + 1) * 64 + lane] = a1;
        Y[(size_t)(nb + r + 2) * 64 + lane] = a2;
        Y[(size_t)(nb + r + 3) * 64 + lane] = a3;
        __syncthreads();
    }
}

// ---------------- gather: T[i] = relu(Y[i] + bias + sum_{e in CSR(i)} Y[src[e]]) ----------------
__global__ __launch_bounds__(256) void gather_kernel(const float* __restrict__ Y,
                                                     const int* __restrict__ row_ptr,
                                                     const int* __restrict__ esrc,
                                                     const float* __restrict__ bias,
                                                     float* __restrict__ T, int N) {
    int wv = threadIdx.x >> 6, lane = threadIdx.x & 63;
    int node = blockIdx.x * 4 + wv;
    if (node >= N) return;
    float acc = Y[(size_t)node * 64 + lane] + bias[lane];
    int e0 = row_ptr[node], e1 = row_ptr[node + 1];
    int e = e0;
    for (; e + 8 <= e1; e += 8) {
        int s0 = esrc[e], s1 = esrc[e + 1], s2 = esrc[e + 2], s3 = esrc[e + 3];
        int s4 = esrc[e + 4], s5 = esrc[e + 5], s6 = esrc[e + 6], s7 = esrc[e + 7];
        float f0 = Y[(size_t)s0 * 64 + lane];
        float f1 = Y[(size_t)s1 * 64 + lane];
        float f2 = Y[(size_t)s2 * 64 + lane];
        float f3 = Y[(size_t)s3 * 64 + lane];
        float f4 = Y[(size_t)s4 * 64 + lane];
        float f5 = Y[(size_t)s5 * 64 + lane];
        float f6 = Y[(size_t)s6 * 64 + lane];
        float f7 = Y[(size_t)s7 * 64 + lane];
        acc += ((f0 + f1) + (f2 + f3)) + ((f4 + f5) + (f6 + f7));
    }
    for (; e < e1; e++) acc += Y[(size_t)esrc[e] * 64 + lane];
    T[(size_t)node * 64 + lane] = fmaxf(acc, 0.f);
}

// ---------------- fused: Y = (relu(bn(T@W1^T + b1))) @ W2^T ----------------
__global__ __launch_bounds__(256) void fused_mlp2_kernel(
    const float* __restrict__ T, const float* __restrict__ W1, const float* __restrict__ b1,
    const float* __restrict__ g, const float* __restrict__ be, const float* __restrict__ m,
    const float* __restrict__ v, const float* __restrict__ W2, float* __restrict__ Y, int N) {
    __shared__ float w1lds[64 * 64];
    __shared__ float w2lds[64 * 64];
    __shared__ float tl[16 * 64];
    __shared__ float hl[16 * 64];
    int tid = threadIdx.x, wv = tid >> 6, lane = tid & 63;
    for (int j = tid; j < 4096; j += 256) {
        int o = j >> 6, k = j & 63;
        int idx = (k >> 2) * 256 + o * 4 + (k & 3);
        w1lds[idx] = W1[j];
        w2lds[idx] = W2[j];
    }
    float bias = b1[lane];
    float s = g[lane] * rsqrtf(v[lane] + BN_EPS);
    float c = be[lane] - m[lane] * s;
    __syncthreads();
    const float4* w14 = (const float4*)w1lds;
    const float4* w24 = (const float4*)w2lds;
    const float4* t4 = (const float4*)tl;
    const float4* h4 = (const float4*)hl;
    for (int nb = blockIdx.x * 16; nb < N; nb += gridDim.x * 16) {
        const float4* tg = (const float4*)(T + (size_t)nb * 64);
        float4* tw = (float4*)tl;
        for (int j = tid; j < 256; j += 256) tw[j] = tg[j];
        __syncthreads();
        int r = wv * 4;
        float a0 = bias, a1 = bias, a2 = bias, a3 = bias;
#pragma unroll
        for (int kb = 0; kb < 16; kb++) {
            float4 w = w14[kb * 64 + lane];
            float4 x0 = t4[(r + 0) * 16 + kb];
            float4 x1 = t4[(r + 1) * 16 + kb];
            float4 x2 = t4[(r + 2) * 16 + kb];
            float4 x3 = t4[(r + 3) * 16 + kb];
            a0 += x0.x * w.x + x0.y * w.y + x0.z * w.z + x0.w * w.w;
            a1 += x1.x * w.x + x1.y * w.y + x1.z * w.z + x1.w * w.w;
            a2 += x2.x * w.x + x2.y * w.y + x2.z * w.z + x2.w * w.w;
            a3 += x3.x * w.x + x3.y * w.y + x3.z * w.z + x3.w * w.w;
        }
        a0 = fmaxf(a0 * s + c, 0.f);
        a1 = fmaxf(a1 * s + c, 0.f);
        a2 = fmaxf(a2 * s + c, 0.f);
        a3 = fmaxf(a3 * s + c, 0.f);
        hl[(r + 0) * 64 + lane] = a0;
        hl[(r + 1) * 64 + lane] = a1;
        hl[(r + 2) * 64 + lane] = a2;
        hl[(r + 3) * 64 + lane] = a3;
        __syncthreads();
        float o0 = 0.f, o1 = 0.f, o2 = 0.f, o3 = 0.f;
#pragma unroll
        for (int kb = 0; kb < 16; kb++) {
            float4 w = w24[kb * 64 + lane];
            float4 x0 = h4[(r + 0) * 16 + kb];
            float4 x1 = h4[(r + 1) * 16 + kb];
            float4 x2 = h4[(r + 2) * 16 + kb];
            float4 x3 = h4[(r + 3) * 16 + kb];
            o0 += x0.x * w.x + x0.y * w.y + x0.z * w.z + x0.w * w.w;
            o1 += x1.x * w.x + x1.y * w.y + x1.z * w.z + x1.w * w.w;
            o2 += x2.x * w.x + x2.y * w.y + x2.z * w.z + x2.w * w.w;
            o3 += x3.x * w.x + x3.y * w.y + x3.z * w.z + x3.w * w.w;
        }
        Y[(size_t)(nb + r + 0) * 64 + lane] = o0;
        Y[(size_t)(nb + r + 1) * 64 + lane] = o1;
        Y[(size_t)(nb + r + 2) * 64 + lane] = o2;
        Y[(size_t)(nb + r + 3) * 64 + lane] = o3;
        __syncthreads();
    }
}

// ---------------- H = relu(bn(T@W^T + b)) ----------------
__global__ __launch_bounds__(256) void fused_mlp1_kernel(
    const float* __restrict__ T, const float* __restrict__ W, const float* __restrict__ b,
    const float* __restrict__ g, const float* __restrict__ be, const float* __restrict__ m,
    const float* __restrict__ v, float* __restrict__ H, int N) {
    __shared__ float wlds[64 * 64];
    __shared__ float tl[16 * 64];
    int tid = threadIdx.x, wv = tid >> 6, lane = tid & 63;
    for (int j = tid; j < 4096; j += 256) {
        int o = j >> 6, k = j & 63;
        wlds[(k >> 2) * 256 + o * 4 + (k & 3)] = W[j];
    }
    float bias = b[lane];
    float s = g[lane] * rsqrtf(v[lane] + BN_EPS);
    float c = be[lane] - m[lane] * s;
    __syncthreads();
    const float4* w4 = (const float4*)wlds;
    const float4* t4 = (const float4*)tl;
    for (int nb = blockIdx.x * 16; nb < N; nb += gridDim.x * 16) {
        const float4* tg = (const float4*)(T + (size_t)nb * 64);
        float4* tw = (float4*)tl;
        for (int j = tid; j < 256; j += 256) tw[j] = tg[j];
        __syncthreads();
        int r = wv * 4;
        float a0 = bias, a1 = bias, a2 = bias, a3 = bias;
#pragma unroll
        for (int kb = 0; kb < 16; kb++) {
            float4 w = w4[kb * 64 + lane];
            float4 x0 = t4[(r + 0) * 16 + kb];
            float4 x1 = t4[(r + 1) * 16 + kb];
            float4 x2 = t4[(r + 2) * 16 + kb];
            float4 x3 = t4[(r + 3) * 16 + kb];
            a0 += x0.x * w.x + x0.y * w.y + x0.z * w.z + x0.w * w.w;
            a1 += x1.x * w.x + x1.y * w.y + x1.z * w.z + x1.w * w.w;
            a2 += x2.x * w.x + x2.y * w.y + x2.z * w.z + x2.w * w.w;
            a3 += x3.x * w.x + x3.y * w.y + x3.z * w.z + x3.w * w.w;
        }
        H[(size_t)(nb + r + 0) * 64 + lane] = fmaxf(a0 * s + c, 0.f);
        H[(size_t)(nb + r + 1) * 64 + lane] = fmaxf(a1 * s + c, 0.f);
        H[(size_t)(nb + r + 2) * 64 + lane] = fmaxf(a2 * s + c, 0.f);
        H[(size_t)(nb + r + 3) * 64 + lane] = fmaxf(a3 * s + c, 0.f);
        __syncthreads();
    }
}

// ---------------- mean pool per graph (batch is sorted) ----------------
__global__ __launch_bounds__(256) void pool_kernel(const float* __restrict__ H,
                                                   const int* __restrict__ batch,
                                                   float* __restrict__ out, int N) {
    __shared__ float part[4][64];
    int g = blockIdx.x;
    int tid = threadIdx.x, wv = tid >> 6, lane = tid & 63;
    int lo = 0, hi = N;
    while (lo < hi) { int mid = (lo + hi) >> 1; if (batch[mid] < g) lo = mid + 1; else hi = mid; }
    int start = lo;
    hi = N;
    while (lo < hi) { int mid = (lo + hi) >> 1; if (batch[mid] < g + 1) lo = mid + 1; else hi = mid; }
    int end = lo;
    float acc = 0.f;
    for (int i = start + wv; i < end; i += 4) acc += H[(size_t)i * 64 + lane];
    part[wv][lane] = acc;
    __syncthreads();
    if (tid < 64) {
        float sfin = part[0][tid] + part[1][tid] + part[2][tid] + part[3][tid];
        float cnt = (float)(end - start);
        out[(size_t)g * 64 + tid] = sfin / fmaxf(cnt, 1.f);
    }
}

extern "C" void kernel_launch(void* const* d_in, const int* in_sizes, int n_in,
                              void* d_out, int out_size, void* d_ws, size_t ws_size,
                              hipStream_t stream) {
    const float* x   = (const float*)d_in[0];
    const int*   ei  = (const int*)d_in[1];   // [2][E], row0=src row1=dst
    const int*   bat = (const int*)d_in[2];
    const float* W1a = (const float*)d_in[3];
    const float* b1a = (const float*)d_in[4];
    const float* W1b = (const float*)d_in[5];
    const float* b1b = (const float*)d_in[6];
    const float* g1  = (const float*)d_in[7];
    const float* be1 = (const float*)d_in[8];
    const float* m1  = (const float*)d_in[9];
    const float* v1  = (const float*)d_in[10];
    const float* W2a = (const float*)d_in[11];
    const float* b2a = (const float*)d_in[12];
    const float* W2b = (const float*)d_in[13];
    const float* b2b = (const float*)d_in[14];
    const float* g2  = (const float*)d_in[15];
    const float* be2 = (const float*)d_in[16];
    const float* m2  = (const float*)d_in[17];
    const float* v2  = (const float*)d_in[18];
    float* out = (float*)d_out;

    int N = in_sizes[0] / 128;
    int E = in_sizes[1] / 2;
    int G = out_size / 64;
    int nbuck = (N + 255) >> 8;

    // workspace layout
    char* ws = (char*)d_ws;
    int* row_ptr = (int*)ws;                       // N+1 (padded)
    int* bcnt = row_ptr + ((N + 1 + 3) & ~3);      // MAXB
    int* boff = bcnt + MAXB;                       // MAXB+1
    int* bpos = boff + MAXB + 4;                   // MAXB
    int* esrc = bpos + MAXB;                       // E
    float* bufA = (float*)(esrc + E);              // N*64
    float* bufB = bufA + (size_t)N * 64;           // N*64
    int* binned = (int*)bufB;                      // aliases bufB (dead until gather#1)

    // CSR build
    hipMemsetAsync(bcnt, 0, MAXB * sizeof(int), stream);
    bin_count<<<128, 256, 0, stream>>>(ei, E, bcnt, nbuck);
    scan_small<<<1, 512, 0, stream>>>(bcnt, boff, bpos, row_ptr + N, nbuck, E);
    bin_scatter<<<(E + CHUNK - 1) / CHUNK, 256, 0, stream>>>(ei, E, bpos, binned, nbuck);
    bucket_csr<<<nbuck, 256, 0, stream>>>(binned, boff, row_ptr, esrc, N);

    // layer 1
    linear_kernel<128><<<2048, 256, 0, stream>>>(x, W1a, bufA, N);
    gather_kernel<<<(N + 3) / 4, 256, 0, stream>>>(bufA, row_ptr, esrc, b1a, bufB, N);
    fused_mlp2_kernel<<<2048, 256, 0, stream>>>(bufB, W1b, b1b, g1, be1, m1, v1, W2a, bufA, N);

    // layer 2
    gather_kernel<<<(N + 3) / 4, 256, 0, stream>>>(bufA, row_ptr, esrc, b2a, bufB, N);
    fused_mlp1_kernel<<<2048, 256, 0, stream>>>(bufB, W2b, b2b, g2, be2, m2, v2, bufA, N);

    // mean pool
    pool_kernel<<<G, 256, 0, stream>>>(bufA, bat, out, N);
}

// Round 4
// 453.257 us; speedup vs baseline: 1.5449x; 1.0656x over previous
//
#include <hip/hip_runtime.h>

#define BN_EPS 1e-5f
#define CHUNK 8192
#define MAXB 512  // max buckets (N up to 131072 with 256 nodes/bucket)

// bf16 helpers (RNE pack, cheap unpack)
__device__ __forceinline__ unsigned short f2bf(float f) {
    unsigned int u = __float_as_uint(f);
    u += 0x7FFF + ((u >> 16) & 1);
    return (unsigned short)(u >> 16);
}
__device__ __forceinline__ float bf2f(unsigned short h) {
    return __uint_as_float((unsigned int)h << 16);
}

// ---------------- CSR build: bucketed, no global random scatter ----------------

__global__ __launch_bounds__(256) void bin_count(const int* __restrict__ ei, int E,
                                                 int* __restrict__ bcnt, int nbuck) {
    __shared__ int h[MAXB];
    for (int i = threadIdx.x; i < nbuck; i += 256) h[i] = 0;
    __syncthreads();
    int i = blockIdx.x * 256 + threadIdx.x, stride = gridDim.x * 256;
    for (int e = i; e < E; e += stride) {
        int d = ei[E + e];
        atomicAdd(&h[d >> 8], 1);
    }
    __syncthreads();
    for (int b = threadIdx.x; b < nbuck; b += 256)
        if (h[b]) atomicAdd(&bcnt[b], h[b]);
}

__global__ __launch_bounds__(512) void scan_small(const int* __restrict__ bcnt,
                                                  int* __restrict__ boff,
                                                  int* __restrict__ bpos,
                                                  int* __restrict__ row_ptr_end,
                                                  int nbuck, int E) {
    __shared__ int wsum[8];
    int tid = threadIdx.x, lane = tid & 63, wv = tid >> 6;
    int val = (tid < nbuck) ? bcnt[tid] : 0;
    int s = val;
#pragma unroll
    for (int off = 1; off < 64; off <<= 1) {
        int t = __shfl_up(s, off, 64);
        if (lane >= off) s += t;
    }
    if (lane == 63) wsum[wv] = s;
    __syncthreads();
    if (wv == 0) {
        int t = (lane < 8) ? wsum[lane] : 0;
#pragma unroll
        for (int off = 1; off < 8; off <<= 1) {
            int u = __shfl_up(t, off, 64);
            if (lane >= off) t += u;
        }
        if (lane < 8) wsum[lane] = t;
    }
    __syncthreads();
    int excl = ((wv == 0) ? 0 : wsum[wv - 1]) + s - val;
    if (tid < nbuck) { boff[tid] = excl; bpos[tid] = excl; }
    if (tid == 0) { boff[nbuck] = E; *row_ptr_end = E; }
}

__global__ __launch_bounds__(256) void bin_scatter(const int* __restrict__ ei, int E,
                                                   int* __restrict__ bpos,
                                                   int* __restrict__ binned, int nbuck) {
    __shared__ int h[MAXB];
    __shared__ int res[MAXB];
    int base = blockIdx.x * CHUNK;
    int cnt = min(CHUNK, E - base);
    for (int b = threadIdx.x; b < nbuck; b += 256) h[b] = 0;
    __syncthreads();
    for (int k = threadIdx.x; k < cnt; k += 256) {
        int d = ei[E + base + k];
        atomicAdd(&h[d >> 8], 1);
    }
    __syncthreads();
    for (int b = threadIdx.x; b < nbuck; b += 256) {
        int c = h[b];
        res[b] = c ? atomicAdd(&bpos[b], c) : 0;
        h[b] = 0;  // reuse as rank counter
    }
    __syncthreads();
    for (int k = threadIdx.x; k < cnt; k += 256) {
        int srcv = ei[base + k];
        int d = ei[E + base + k];
        int b = d >> 8;
        int r = atomicAdd(&h[b], 1);
        binned[res[b] + r] = ((d & 255) << 17) | srcv;  // src < 2^17
    }
}

__global__ __launch_bounds__(256) void bucket_csr(const int* __restrict__ binned,
                                                  const int* __restrict__ boff,
                                                  int* __restrict__ row_ptr,
                                                  int* __restrict__ esrc, int N) {
    __shared__ int ncnt[256];
    __shared__ int npos[256];
    __shared__ int wsum[4];
    int b = blockIdx.x, tid = threadIdx.x, lane = tid & 63, wv = tid >> 6;
    int lo = boff[b], hi = boff[b + 1];
    int base_node = b << 8;
    ncnt[tid] = 0;
    __syncthreads();
    for (int i = lo + tid; i < hi; i += 256)
        atomicAdd(&ncnt[binned[i] >> 17], 1);
    __syncthreads();
    int c = ncnt[tid];
    int s = c;
#pragma unroll
    for (int off = 1; off < 64; off <<= 1) {
        int t = __shfl_up(s, off, 64);
        if (lane >= off) s += t;
    }
    if (lane == 63) wsum[wv] = s;
    __syncthreads();
    int woff = 0;
#pragma unroll
    for (int i = 0; i < 4; i++) woff += (i < wv) ? wsum[i] : 0;
    int abspos = lo + woff + (s - c);
    if (base_node + tid < N) row_ptr[base_node + tid] = abspos;
    npos[tid] = abspos;
    __syncthreads();
    for (int i = lo + tid; i < hi; i += 256) {
        int val = binned[i];
        int r = atomicAdd(&npos[val >> 17], 1);
        esrc[r] = val & 0x1FFFF;
    }
}

// ---------------- dense: Y[n][64](bf16) = X[n][K](f32) @ W[64][K]^T ----------------
template <int K>
__global__ __launch_bounds__(256) void linear_kernel(const float* __restrict__ X,
                                                     const float* __restrict__ W,
                                                     unsigned short* __restrict__ Y, int N) {
    __shared__ float wlds[K * 64];
    __shared__ float xlds[16 * K];
    int tid = threadIdx.x;
    for (int j = tid; j < 64 * K; j += 256) {
        int o = j / K, k = j % K;
        wlds[(k >> 2) * 256 + o * 4 + (k & 3)] = W[j];
    }
    __syncthreads();
    const float4* w4p = (const float4*)wlds;
    const float4* x4p = (const float4*)xlds;
    int wv = tid >> 6, lane = tid & 63;
    for (int nb = blockIdx.x * 16; nb < N; nb += gridDim.x * 16) {
        const float4* xg = (const float4*)(X + (size_t)nb * K);
        float4* xl = (float4*)xlds;
        for (int j = tid; j < 16 * K / 4; j += 256) xl[j] = xg[j];
        __syncthreads();
        int r = wv * 4;
        float a0 = 0.f, a1 = 0.f, a2 = 0.f, a3 = 0.f;
#pragma unroll 8
        for (int kb = 0; kb < K / 4; kb++) {
            float4 w = w4p[kb * 64 + lane];
            float4 x0 = x4p[(r + 0) * (K / 4) + kb];
            float4 x1 = x4p[(r + 1) * (K / 4) + kb];
            float4 x2 = x4p[(r + 2) * (K / 4) + kb];
            float4 x3 = x4p[(r + 3) * (K / 4) + kb];
            a0 += x0.x * w.x + x0.y * w.y + x0.z * w.z + x0.w * w.w;
            a1 += x1.x * w.x + x1.y * w.y + x1.z * w.z + x1.w * w.w;
            a2 += x2.x * w.x + x2.y * w.y + x2.z * w.z + x2.w * w.w;
            a3 += x3.x * w.x + x3.y * w.y + x3.z * w.z + x3.w * w.w;
        }
        Y[(size_t)(nb + r + 0) * 64 + lane] = f2bf(a0);
        Y[(size_t)(nb + r + 1) * 64 + lane] = f2bf(a1);
        Y[(size_t)(nb + r + 2) * 64 + lane] = f2bf(a2);
        Y[(size_t)(nb + r + 3) * 64 + lane] = f2bf(a3);
        __syncthreads();
    }
}

// ---------------- gather: T[i](bf16) = relu(Y[i] + bias + sum_{e} Y[src[e]]) ----------------
__global__ __launch_bounds__(256) void gather_kernel(const unsigned short* __restrict__ Y,
                                                     const int* __restrict__ row_ptr,
                                                     const int* __restrict__ esrc,
                                                     const float* __restrict__ bias,
                                                     unsigned short* __restrict__ T, int N) {
    int wv = threadIdx.x >> 6, lane = threadIdx.x & 63;
    int node = blockIdx.x * 4 + wv;
    if (node >= N) return;
    float acc = bf2f(Y[(size_t)node * 64 + lane]) + bias[lane];
    int e0 = row_ptr[node], e1 = row_ptr[node + 1];
    int e = e0;
    for (; e + 8 <= e1; e += 8) {
        int s0 = esrc[e], s1 = esrc[e + 1], s2 = esrc[e + 2], s3 = esrc[e + 3];
        int s4 = esrc[e + 4], s5 = esrc[e + 5], s6 = esrc[e + 6], s7 = esrc[e + 7];
        float f0 = bf2f(Y[(size_t)s0 * 64 + lane]);
        float f1 = bf2f(Y[(size_t)s1 * 64 + lane]);
        float f2 = bf2f(Y[(size_t)s2 * 64 + lane]);
        float f3 = bf2f(Y[(size_t)s3 * 64 + lane]);
        float f4 = bf2f(Y[(size_t)s4 * 64 + lane]);
        float f5 = bf2f(Y[(size_t)s5 * 64 + lane]);
        float f6 = bf2f(Y[(size_t)s6 * 64 + lane]);
        float f7 = bf2f(Y[(size_t)s7 * 64 + lane]);
        acc += ((f0 + f1) + (f2 + f3)) + ((f4 + f5) + (f6 + f7));
    }
    for (; e < e1; e++) acc += bf2f(Y[(size_t)esrc[e] * 64 + lane]);
    T[(size_t)node * 64 + lane] = f2bf(fmaxf(acc, 0.f));
}

// stage 16 nodes x 64 feats of bf16 into f32 LDS tile
__device__ __forceinline__ void stage_bf16_tile(const unsigned short* __restrict__ src,
                                                float* __restrict__ dst, int tid) {
    const ushort4* s4 = (const ushort4*)src;
    ushort4 u = s4[tid];  // 256 threads x 4 elems = 1024
    float4* d4 = (float4*)dst;
    d4[tid] = make_float4(bf2f(u.x), bf2f(u.y), bf2f(u.z), bf2f(u.w));
}

// ---------------- fused: Y(bf16) = (relu(bn(T@W1^T + b1))) @ W2^T ----------------
__global__ __launch_bounds__(256) void fused_mlp2_kernel(
    const unsigned short* __restrict__ T, const float* __restrict__ W1,
    const float* __restrict__ b1, const float* __restrict__ g, const float* __restrict__ be,
    const float* __restrict__ m, const float* __restrict__ v, const float* __restrict__ W2,
    unsigned short* __restrict__ Y, int N) {
    __shared__ float w1lds[64 * 64];
    __shared__ float w2lds[64 * 64];
    __shared__ float tl[16 * 64];
    __shared__ float hl[16 * 64];
    int tid = threadIdx.x, wv = tid >> 6, lane = tid & 63;
    for (int j = tid; j < 4096; j += 256) {
        int o = j >> 6, k = j & 63;
        int idx = (k >> 2) * 256 + o * 4 + (k & 3);
        w1lds[idx] = W1[j];
        w2lds[idx] = W2[j];
    }
    float bias = b1[lane];
    float s = g[lane] * rsqrtf(v[lane] + BN_EPS);
    float c = be[lane] - m[lane] * s;
    __syncthreads();
    const float4* w14 = (const float4*)w1lds;
    const float4* w24 = (const float4*)w2lds;
    const float4* t4 = (const float4*)tl;
    const float4* h4 = (const float4*)hl;
    for (int nb = blockIdx.x * 16; nb < N; nb += gridDim.x * 16) {
        stage_bf16_tile(T + (size_t)nb * 64, tl, tid);
        __syncthreads();
        int r = wv * 4;
        float a0 = bias, a1 = bias, a2 = bias, a3 = bias;
#pragma unroll
        for (int kb = 0; kb < 16; kb++) {
            float4 w = w14[kb * 64 + lane];
            float4 x0 = t4[(r + 0) * 16 + kb];
            float4 x1 = t4[(r + 1) * 16 + kb];
            float4 x2 = t4[(r + 2) * 16 + kb];
            float4 x3 = t4[(r + 3) * 16 + kb];
            a0 += x0.x * w.x + x0.y * w.y + x0.z * w.z + x0.w * w.w;
            a1 += x1.x * w.x + x1.y * w.y + x1.z * w.z + x1.w * w.w;
            a2 += x2.x * w.x + x2.y * w.y + x2.z * w.z + x2.w * w.w;
            a3 += x3.x * w.x + x3.y * w.y + x3.z * w.z + x3.w * w.w;
        }
        a0 = fmaxf(a0 * s + c, 0.f);
        a1 = fmaxf(a1 * s + c, 0.f);
        a2 = fmaxf(a2 * s + c, 0.f);
        a3 = fmaxf(a3 * s + c, 0.f);
        hl[(r + 0) * 64 + lane] = a0;
        hl[(r + 1) * 64 + lane] = a1;
        hl[(r + 2) * 64 + lane] = a2;
        hl[(r + 3) * 64 + lane] = a3;
        __syncthreads();
        float o0 = 0.f, o1 = 0.f, o2 = 0.f, o3 = 0.f;
#pragma unroll
        for (int kb = 0; kb < 16; kb++) {
            float4 w = w24[kb * 64 + lane];
            float4 x0 = h4[(r + 0) * 16 + kb];
            float4 x1 = h4[(r + 1) * 16 + kb];
            float4 x2 = h4[(r + 2) * 16 + kb];
            float4 x3 = h4[(r + 3) * 16 + kb];
            o0 += x0.x * w.x + x0.y * w.y + x0.z * w.z + x0.w * w.w;
            o1 += x1.x * w.x + x1.y * w.y + x1.z * w.z + x1.w * w.w;
            o2 += x2.x * w.x + x2.y * w.y + x2.z * w.z + x2.w * w.w;
            o3 += x3.x * w.x + x3.y * w.y + x3.z * w.z + x3.w * w.w;
        }
        Y[(size_t)(nb + r + 0) * 64 + lane] = f2bf(o0);
        Y[(size_t)(nb + r + 1) * 64 + lane] = f2bf(o1);
        Y[(size_t)(nb + r + 2) * 64 + lane] = f2bf(o2);
        Y[(size_t)(nb + r + 3) * 64 + lane] = f2bf(o3);
        __syncthreads();
    }
}

// ---------------- H(bf16) = relu(bn(T@W^T + b)) ----------------
__global__ __launch_bounds__(256) void fused_mlp1_kernel(
    const unsigned short* __restrict__ T, const float* __restrict__ W,
    const float* __restrict__ b, const float* __restrict__ g, const float* __restrict__ be,
    const float* __restrict__ m, const float* __restrict__ v,
    unsigned short* __restrict__ H, int N) {
    __shared__ float wlds[64 * 64];
    __shared__ float tl[16 * 64];
    int tid = threadIdx.x, wv = tid >> 6, lane = tid & 63;
    for (int j = tid; j < 4096; j += 256) {
        int o = j >> 6, k = j & 63;
        wlds[(k >> 2) * 256 + o * 4 + (k & 3)] = W[j];
    }
    float bias = b[lane];
    float s = g[lane] * rsqrtf(v[lane] + BN_EPS);
    float c = be[lane] - m[lane] * s;
    __syncthreads();
    const float4* w4 = (const float4*)wlds;
    const float4* t4 = (const float4*)tl;
    for (int nb = blockIdx.x * 16; nb < N; nb += gridDim.x * 16) {
        stage_bf16_tile(T + (size_t)nb * 64, tl, tid);
        __syncthreads();
        int r = wv * 4;
        float a0 = bias, a1 = bias, a2 = bias, a3 = bias;
#pragma unroll
        for (int kb = 0; kb < 16; kb++) {
            float4 w = w4[kb * 64 + lane];
            float4 x0 = t4[(r + 0) * 16 + kb];
            float4 x1 = t4[(r + 1) * 16 + kb];
            float4 x2 = t4[(r + 2) * 16 + kb];
            float4 x3 = t4[(r + 3) * 16 + kb];
            a0 += x0.x * w.x + x0.y * w.y + x0.z * w.z + x0.w * w.w;
            a1 += x1.x * w.x + x1.y * w.y + x1.z * w.z + x1.w * w.w;
            a2 += x2.x * w.x + x2.y * w.y + x2.z * w.z + x2.w * w.w;
            a3 += x3.x * w.x + x3.y * w.y + x3.z * w.z + x3.w * w.w;
        }
        H[(size_t)(nb + r + 0) * 64 + lane] = f2bf(fmaxf(a0 * s + c, 0.f));
        H[(size_t)(nb + r + 1) * 64 + lane] = f2bf(fmaxf(a1 * s + c, 0.f));
        H[(size_t)(nb + r + 2) * 64 + lane] = f2bf(fmaxf(a2 * s + c, 0.f));
        H[(size_t)(nb + r + 3) * 64 + lane] = f2bf(fmaxf(a3 * s + c, 0.f));
        __syncthreads();
    }
}

// ---------------- mean pool per graph (batch is sorted) ----------------
__global__ __launch_bounds__(256) void pool_kernel(const unsigned short* __restrict__ H,
                                                   const int* __restrict__ batch,
                                                   float* __restrict__ out, int N) {
    __shared__ float part[4][64];
    int g = blockIdx.x;
    int tid = threadIdx.x, wv = tid >> 6, lane = tid & 63;
    int lo = 0, hi = N;
    while (lo < hi) { int mid = (lo + hi) >> 1; if (batch[mid] < g) lo = mid + 1; else hi = mid; }
    int start = lo;
    hi = N;
    while (lo < hi) { int mid = (lo + hi) >> 1; if (batch[mid] < g + 1) lo = mid + 1; else hi = mid; }
    int end = lo;
    float acc = 0.f;
    for (int i = start + wv; i < end; i += 4) acc += bf2f(H[(size_t)i * 64 + lane]);
    part[wv][lane] = acc;
    __syncthreads();
    if (tid < 64) {
        float sfin = part[0][tid] + part[1][tid] + part[2][tid] + part[3][tid];
        float cnt = (float)(end - start);
        out[(size_t)g * 64 + tid] = sfin / fmaxf(cnt, 1.f);
    }
}

extern "C" void kernel_launch(void* const* d_in, const int* in_sizes, int n_in,
                              void* d_out, int out_size, void* d_ws, size_t ws_size,
                              hipStream_t stream) {
    const float* x   = (const float*)d_in[0];
    const int*   ei  = (const int*)d_in[1];
    const int*   bat = (const int*)d_in[2];
    const float* W1a = (const float*)d_in[3];
    const float* b1a = (const float*)d_in[4];
    const float* W1b = (const float*)d_in[5];
    const float* b1b = (const float*)d_in[6];
    const float* g1  = (const float*)d_in[7];
    const float* be1 = (const float*)d_in[8];
    const float* m1  = (const float*)d_in[9];
    const float* v1  = (const float*)d_in[10];
    const float* W2a = (const float*)d_in[11];
    const float* b2a = (const float*)d_in[12];
    const float* W2b = (const float*)d_in[13];
    const float* b2b = (const float*)d_in[14];
    const float* g2  = (const float*)d_in[15];
    const float* be2 = (const float*)d_in[16];
    const float* m2  = (const float*)d_in[17];
    const float* v2  = (const float*)d_in[18];
    float* out = (float*)d_out;

    int N = in_sizes[0] / 128;
    int E = in_sizes[1] / 2;
    int G = out_size / 64;
    int nbuck = (N + 255) >> 8;

    // workspace layout (bf16 feature buffers)
    char* ws = (char*)d_ws;
    int* row_ptr = (int*)ws;                              // N+1 (padded)
    int* bcnt = row_ptr + ((N + 1 + 3) & ~3);             // MAXB
    int* boff = bcnt + MAXB;                              // MAXB+1
    int* bpos = boff + MAXB + 4;                          // MAXB
    int* esrc = bpos + MAXB;                              // E
    unsigned short* bufA = (unsigned short*)(esrc + E);   // N*64 bf16
    unsigned short* bufB = bufA + (size_t)N * 64;         // N*64 bf16
    int* binned = (int*)bufB;                             // aliases bufB (dead until gather#1)

    // CSR build
    hipMemsetAsync(bcnt, 0, MAXB * sizeof(int), stream);
    bin_count<<<512, 256, 0, stream>>>(ei, E, bcnt, nbuck);
    scan_small<<<1, 512, 0, stream>>>(bcnt, boff, bpos, row_ptr + N, nbuck, E);
    bin_scatter<<<(E + CHUNK - 1) / CHUNK, 256, 0, stream>>>(ei, E, bpos, binned, nbuck);
    bucket_csr<<<nbuck, 256, 0, stream>>>(binned, boff, row_ptr, esrc, N);

    // layer 1
    linear_kernel<128><<<2048, 256, 0, stream>>>(x, W1a, bufA, N);
    gather_kernel<<<(N + 3) / 4, 256, 0, stream>>>(bufA, row_ptr, esrc, b1a, bufB, N);
    fused_mlp2_kernel<<<2048, 256, 0, stream>>>(bufB, W1b, b1b, g1, be1, m1, v1, W2a, bufA, N);

    // layer 2
    gather_kernel<<<(N + 3) / 4, 256, 0, stream>>>(bufA, row_ptr, esrc, b2a, bufB, N);
    fused_mlp1_kernel<<<2048, 256, 0, stream>>>(bufB, W2b, b2b, g2, be2, m2, v2, bufA, N);

    // mean pool
    pool_kernel<<<G, 256, 0, stream>>>(bufA, bat, out, N);
}